// Round 6
// baseline (212.515 us; speedup 1.0000x reference)
//
#include <hip/hip_runtime.h>

// Problem constants (from reference setup_inputs)
constexpr int B = 16;
constexpr int D = 256;
constexpr int K = 18;
constexpr int SZ = 128;
constexpr int S = SZ * SZ;      // 16384 positions per plane
constexpr int N = S / 2;        // 8192 sampled positions
constexpr int PB = 64;          // positions per block (fused kernel)

// ---------------------------------------------------------------------------
// Prep: blocks 0..31 scatter mask ones (mask pre-zeroed by memset);
// blocks 32..103 compute p2[b*K+k] = ||proto||^2 fp64 (one row per warp);
// blocks 104..391 transpose proto -> proto64[b][d][k] fp64 (for wave-uniform
// scalar loads in the fused kernel's dot phase).
// ---------------------------------------------------------------------------
__global__ __launch_bounds__(256) void prep_kernel(
    const float* __restrict__ proto,
    const int* __restrict__ idx,
    unsigned char* __restrict__ mask,
    double* __restrict__ p2,
    double* __restrict__ p64) {
  const int blk = blockIdx.x;
  if (blk < 32) {
    mask[idx[blk * 256 + threadIdx.x]] = 1;   // indices are a permutation
  } else if (blk < 104) {
    const int row  = (blk - 32) * 4 + (threadIdx.x >> 6);  // 0..287 = b*K+k
    const int lane = threadIdx.x & 63;
    const float4 v = *(const float4*)(proto + (size_t)row * D + lane * 4);
    double s = (double)v.x * (double)v.x + (double)v.y * (double)v.y
             + (double)v.z * (double)v.z + (double)v.w * (double)v.w;
#pragma unroll
    for (int off = 1; off < 64; off <<= 1)
      s += __shfl_xor(s, off, 64);
    if (lane == 0) p2[row] = s;
  } else {
    const int e = (blk - 104) * 256 + threadIdx.x;   // 0..B*D*K-1 exactly
    const int b = e / (D * K);
    const int r = e - b * (D * K);
    const int d = r / K;
    const int k = r - d * K;
    p64[e] = (double)proto[((size_t)b * K + k) * D + d];
  }
}

// ---------------------------------------------------------------------------
// Fused argmin + output. Block = (b, 64-position chunk), 256 threads.
//  stage:  f tile [256 d][64 pos] -> 64 KiB LDS, fully coalesced.
//  dots:   wave w covers d in [64w,64w+64), lane = position; all 18 k per
//          lane; proto64[b][d][k] via wave-uniform scalar loads (SGPR operand
//          of v_fma_f64); f from LDS (1 ds_read_b32/d, 2-way bank = free).
//  reduce: 3 chunks of 6 k through 12 KiB LDS, fixed ((w0+w1)+w2)+w3 order;
//          argmin with strict < over ascending k = numpy first-min.
//  output: wave w writes its d-range: mask ? proto[kstar][d] : f (from LDS).
// Reads assp exactly once, writes out exactly once.
// ---------------------------------------------------------------------------
__global__ __launch_bounds__(256) void fused_kernel(
    const float* __restrict__ assp,
    const float* __restrict__ proto,
    const double* __restrict__ p64,
    const double* __restrict__ p2,
    const unsigned char* __restrict__ mask,
    float* __restrict__ out) {
  __shared__ float  fs[D][PB];        // 64 KiB
  __shared__ double red[4][6][PB];    // 12 KiB

  const int b     = blockIdx.x & 15;    // batches spread across XCDs
  const int chunk = blockIdx.x >> 4;    // 0..255
  const int pos0  = chunk * PB;
  const int w     = __builtin_amdgcn_readfirstlane(threadIdx.x >> 6); // wave id (uniform)
  const int lane  = threadIdx.x & 63;   // = position within chunk

  // ---- stage f tile (all 4 waves, coalesced: 16 lanes x 256B per d-row) ----
  const float* fin = assp + (size_t)(b * D) * S + pos0;
  {
    const int dr = threadIdx.x >> 4;    // 0..15
    const int p4 = threadIdx.x & 15;    // float4 column
    for (int i = 0; i < 16; i += 4) {
      float4 v[4];
#pragma unroll
      for (int j = 0; j < 4; ++j)
        v[j] = *(const float4*)(fin + (size_t)((i + j) * 16 + dr) * S + p4 * 4);
#pragma unroll
      for (int j = 0; j < 4; ++j)
        *(float4*)&fs[(i + j) * 16 + dr][p4 * 4] = v[j];
    }
  }
  __syncthreads();

  // ---- dots: 64 d per wave, 18 k per lane, proto via scalar loads ----
  double acc[K];
#pragma unroll
  for (int k = 0; k < K; ++k) acc[k] = 0.0;
  const double* pw = p64 + ((size_t)b * D + w * 64) * K;
  for (int i = 0; i < 64; ++i) {
    const double f = (double)fs[w * 64 + i][lane];
    const double* pr = pw + i * K;      // uniform address -> s_load
#pragma unroll
    for (int k = 0; k < K; ++k) acc[k] += f * pr[k];
  }

  // ---- cross-wave reduce + argmin (every lane computes kstar for its pos) --
  const double* p2b = p2 + b * K;
  double best = 1e300;
  int kstar = 0;
  for (int c = 0; c < 3; ++c) {
    __syncthreads();
#pragma unroll
    for (int j = 0; j < 6; ++j) red[w][j][lane] = acc[c * 6 + j];
    __syncthreads();
#pragma unroll
    for (int j = 0; j < 6; ++j) {
      const double s = ((red[0][j][lane] + red[1][j][lane]) + red[2][j][lane])
                     + red[3][j][lane];
      const double d2 = p2b[c * 6 + j] - 2.0 * s;
      if (d2 < best) { best = d2; kstar = c * 6 + j; }  // strict <, k ascending
    }
  }

  // ---- output: wave w writes its d-range for all 64 positions ----
  const int m = mask[pos0 + lane];
  float* op = out + ((size_t)(b * D + w * 64)) * S + pos0;
  const float* pkf = proto + ((size_t)(b * K + kstar)) * D + w * 64;  // per-lane row
  for (int i = 0; i < 64; i += 4) {
    const float4 pv = *(const float4*)(pkf + i);   // 16B gather, L1-hot (18 KB)
    const float f0 = fs[w * 64 + i + 0][lane];
    const float f1 = fs[w * 64 + i + 1][lane];
    const float f2 = fs[w * 64 + i + 2][lane];
    const float f3 = fs[w * 64 + i + 3][lane];
    op[(size_t)(i + 0) * S + lane] = m ? pv.x : f0;
    op[(size_t)(i + 1) * S + lane] = m ? pv.y : f1;
    op[(size_t)(i + 2) * S + lane] = m ? pv.z : f2;
    op[(size_t)(i + 3) * S + lane] = m ? pv.w : f3;
  }
}

extern "C" void kernel_launch(void* const* d_in, const int* in_sizes, int n_in,
                              void* d_out, int out_size, void* d_ws, size_t ws_size,
                              hipStream_t stream) {
  const float* assp  = (const float*)d_in[0];
  const float* proto = (const float*)d_in[1];
  const int*   idx   = (const int*)d_in[2];
  float* out = (float*)d_out;

  // ws layout: [mask: S bytes][p2: B*K doubles][proto64: B*D*K doubles]
  unsigned char* mask = (unsigned char*)d_ws;
  double*        p2   = (double*)((char*)d_ws + S);
  double*        p64  = (double*)((char*)d_ws + S + (size_t)B * K * 8);

  hipMemsetAsync(mask, 0, S, stream);   // 16 KiB
  prep_kernel<<<392, 256, 0, stream>>>(proto, idx, mask, p2, p64);
  fused_kernel<<<B * (S / PB), 256, 0, stream>>>(assp, proto, p64, p2, mask, out);
}